// Round 13
// baseline (395.456 us; speedup 1.0000x reference)
//
#include <hip/hip_runtime.h>
#include <string.h>

// TopographicIntentMap R13: quad-row ds_read_b128 gathers + nnz-sorted balance.
// Evidence: R7 (b32) vs R10/R12 (b64) shows wall tracks DS gather cost; DS
// floor = 2506 x 5.8cy x 30 = 436K cyc/CU. One b128 serves FOUR rows (lanes
// 0-15 row a, ..., 48-63 row d; each lane 4 batches x 16B): 12cy per 4 rows
// vs 23.2 -> DS halves+. Prep sorts rows by nnz (deterministic rank sort):
// 32 quads of 4 similar-length rows (pad to group max, ~5%), 16 shortest rows
// are solo (R7's proven b32 path); wave w gets quads {w, 31-w} + solo w ->
// balanced waves (attacks the 2x barrier-convoy gap).
// Hazards avoided (R8-R12 lessons): ONE tick body, runtime buffer fold, no
// bit packing, no per-entry cross-unit ops, rotation-free padded loops, solo
// stream keeps the vz vector-VMEM trick (quad stream is per-lane already).
// Numerics: same exact-f64 pipeline as R3-R12 (absmax 0 every round); per
// (row,batch) rec chain k-ascending; pads +0.0*acc[0]; LIF formulas verbatim.

#define NN 144
#define NE 115
#define NB 64            // batches per block (= lanes)
#define THREADS 1024     // 16 waves; each wave: 2 quads (8 rows) + 1 solo row

#define QUAD_BASE 4096   // quad stream: 32 quads, k-slabs of 32B (4 x {colByte,w})
#define SOLO_BASE 53248  // solo stream: 16 rows, 8B entries {colByte,w}
#define REGION_END 61440

__device__ __forceinline__ float u2f(unsigned u) {
    float f; memcpy(&f, &u, 4); return f;
}

__global__ void prep_kernel(const float* __restrict__ W_rec,
                            int* __restrict__ meta, char* __restrict__ wsB) {
    __shared__ int cnt[NN];
    __shared__ int sorted[NN];
    __shared__ int kqS[32], ksS[16], qOS[32], sOS[16];
    const int t = threadIdx.x;

    // zero the whole stream region (pads + prefetch-overrun tails)
    for (int i = t; i < (REGION_END - QUAD_BASE) / 4; i += 256)
        ((int*)(wsB + QUAD_BASE))[i] = 0;

    if (t < NN) {
        int c = 0;
        for (int j = 0; j < NN; ++j) c += (W_rec[t * NN + j] != 0.0f);
        cnt[t] = c;
    }
    __syncthreads();
    if (t < NN) {   // deterministic descending rank (ties by index)
        int ct = cnt[t], r = 0;
        for (int j = 0; j < NN; ++j) {
            int cj = cnt[j];
            r += (cj > ct) || (cj == ct && j < t);
        }
        sorted[r] = t;
    }
    __syncthreads();
    if (t == 0) {
        int off = 0;
        for (int q = 0; q < 32; ++q) {
            int mx = cnt[sorted[4 * q]];           // desc: first = group max
            int kq = ((mx < 1 ? 1 : mx) + 3) & ~3;
            kqS[q] = kq; qOS[q] = off; off += kq * 32;
        }
        int so = 0;
        for (int s = 0; s < 16; ++s) {
            int c = cnt[sorted[128 + s]];
            int ks = ((c < 1 ? 1 : c) + 3) & ~3;
            ksS[s] = ks; sOS[s] = so; so += ks * 8;
        }
    }
    __syncthreads();
    if (t < 128) {          // quad streams: q = t>>2, sub-row i = t&3
        int q = t >> 2, i = t & 3, R = sorted[4 * q + i];
        char* base = wsB + QUAD_BASE + qOS[q] + i * 8;
        int k = 0;
        for (int j = 0; j < NN; ++j) {
            float w = W_rec[R * NN + j];
            if (w != 0.0f) {
                *(unsigned*)(base + (size_t)k * 32)    = (unsigned)j * 256u;
                *(float*)(base + (size_t)k * 32 + 4)   = w;
                ++k;
            }
        }
    } else if (t < 144) {   // solo streams
        int s = t - 128, R = sorted[128 + s];
        char* base = wsB + SOLO_BASE + sOS[s];
        int k = 0;
        for (int j = 0; j < NN; ++j) {
            float w = W_rec[R * NN + j];
            if (w != 0.0f) {
                *(unsigned*)(base + (size_t)k * 8)   = (unsigned)j * 256u;
                *(float*)(base + (size_t)k * 8 + 4)  = w;
                ++k;
            }
        }
    }
    if (t < 16) {           // per-wave metadata: quads {w, 31-w}, solo w
        int w = t;
        int* m = meta + w * 16;
        m[0] = qOS[w];      m[1] = kqS[w];
        m[2] = qOS[31 - w]; m[3] = kqS[31 - w];
        for (int i = 0; i < 4; ++i) m[4 + i] = sorted[4 * w + i];
        for (int i = 0; i < 4; ++i) m[8 + i] = sorted[4 * (31 - w) + i];
        m[12] = sOS[w]; m[13] = ksS[w]; m[14] = sorted[128 + w];
    }
}

// one k-slab: 4 batches of one row via ds_read_b128; 4 independent f64 chains
#define QF(S)                                                           \
    {                                                                   \
        float4 a4 = *(const float4*)(ldsB + ((S).x + lroQ));            \
        double wq = (double)u2f((S).y);                                 \
        RQ0 += wq * (double)a4.x;                                       \
        RQ1 += wq * (double)a4.y;                                       \
        RQ2 += wq * (double)a4.z;                                       \
        RQ3 += wq * (double)a4.w;                                       \
    }

#define QUAD_SEC(QOFF, QK, ROW, DRV, VQ, AQ)                            \
    {                                                                   \
        const uint2* p = (const uint2*)(wsQ + (QOFF)) + sub;            \
        uint2 S0 = p[0], S1 = p[4], S2 = p[8], S3 = p[12];              \
        double RQ0 = 0.0, RQ1 = 0.0, RQ2 = 0.0, RQ3 = 0.0;              \
        for (int k = 0; k + 4 <= (QK); k += 4) {                        \
            QF(S0); S0 = p[16];                                         \
            QF(S1); S1 = p[20];                                         \
            QF(S2); S2 = p[24];                                         \
            QF(S3); S3 = p[28];                                         \
            p += 16;                                                    \
        }                                                               \
        const bool exc = (ROW) < NE;                                    \
        double recs[4] = {RQ0, RQ1, RQ2, RQ3};                          \
        _Pragma("unroll")                                               \
        for (int j = 0; j < 4; ++j) {                                   \
            double rec = recs[j];                                       \
            double x = (DRV)[j] + 0.3 * (exc ? rec : -rec);             \
            double vv = (VQ)[j];                                        \
            vv += (x - vv) * 0.5;                                       \
            double sd = (vv >= 1.0) ? 1.0 : 0.0;                        \
            vv *= (1.0 - sd);                                           \
            (VQ)[j] = vv;                                               \
            (AQ)[j] += (float)sd;                                       \
        }                                                               \
        float4 st; st.x=(AQ)[0]; st.y=(AQ)[1]; st.z=(AQ)[2]; st.w=(AQ)[3]; \
        *(float4*)(WbB + (unsigned)(ROW) * 256u + ((lane & 15) * 16)) = st; \
    }

// 4 solo entries from two uint4 regs (R7's proven b32 path)
#define GS4(S0, S1)                                                     \
    {                                                                   \
        float a0 = *(const float*)(ldsB + ((S0).x + lroS));             \
        float a1 = *(const float*)(ldsB + ((S0).z + lroS));             \
        float a2 = *(const float*)(ldsB + ((S1).x + lroS));             \
        float a3 = *(const float*)(ldsB + ((S1).z + lroS));             \
        recS += (double)u2f((S0).y) * (double)a0;                       \
        recS += (double)u2f((S0).w) * (double)a1;                       \
        recS += (double)u2f((S1).y) * (double)a2;                       \
        recS += (double)u2f((S1).w) * (double)a3;                       \
    }

__global__ __launch_bounds__(THREADS) void snn_kernel(
        const int*   __restrict__ actions,
        const float* __restrict__ spk,      // [B,8,115]
        const float* __restrict__ W_inh,    // [144,115]
        const int*   __restrict__ meta,
        const char*  __restrict__ wsB,
        const int*   __restrict__ nt_ptr,
        float*       __restrict__ out,      // [B,115]
        int B) {
    __shared__ __align__(16) float accF[2][NN * NB];   // 73728 B double-buffer

    const char* ldsB = (const char*)&accF[0][0];
    char*       nbB  = (char*)&accF[1][0];   // nb sums alias buffer1 (pre-loop)
    const char* wsQ  = wsB + QUAD_BASE;
    const char* wsS  = wsB + SOLO_BASE;

    const int t    = threadIdx.x;
    const int lane = t & 63;
    const int wid  = t >> 6;
    const int sub  = lane >> 4;              // 0..3 sub-row within quad
    const int b0   = blockIdx.x * NB;
    const int ticks = *nt_ptr;

    const int* mw = meta + wid * 16;         // wave-uniform metadata
    const int qO0 = mw[0], qk0 = mw[1], qO1 = mw[2], qk1 = mw[3];
    const int r0  = mw[4 + sub];
    const int r1  = mw[8 + sub];
    const int sO  = mw[12], sk = mw[13], srow = mw[14];

    int vz;                                  // vector-VMEM path for solo stream
    asm volatile("v_mov_b32 %0, 0" : "=v"(vz));

    // stage neighbor sums nb[e][bb] (stride 64 f32, 16B-aligned rows)
    for (int p = t; p < NB * NE; p += THREADS) {
        int bb = p / NE;
        int e  = p - bb * NE;
        float s = 0.0f;
        if (b0 + bb < B) {
            const float* sp = spk + ((size_t)(b0 + bb) * 8) * NE + e;
            #pragma unroll
            for (int n = 0; n < 8; ++n) s += sp[n * NE];
        }
        *(float*)(nbB + (size_t)e * 256 + (size_t)bb * 4) = s;
    }
    for (int i = t; i < NN * NB; i += THREADS) accF[0][i] = 0.0f;
    __syncthreads();

    // drives (fp64, e ascending — same association as R4-R12)
    double inh0[4] = {0,0,0,0}, inh1[4] = {0,0,0,0}, inhS = 0.0;
    for (int e = 0; e < NE; ++e) {
        float4 nb4 = *(const float4*)(nbB + e * 256 + (lane & 15) * 16);
        float  nbs = *(const float*)(nbB + e * 256 + lane * 4);
        double w0 = (double)W_inh[r0 * NE + e];
        double w1 = (double)W_inh[r1 * NE + e];
        double w2 = (double)W_inh[srow * NE + e];
        inh0[0] += (double)nb4.x * w0; inh0[1] += (double)nb4.y * w0;
        inh0[2] += (double)nb4.z * w0; inh0[3] += (double)nb4.w * w0;
        inh1[0] += (double)nb4.x * w1; inh1[1] += (double)nb4.y * w1;
        inh1[2] += (double)nb4.z * w1; inh1[3] += (double)nb4.w * w1;
        inhS += (double)nbs * w2;
    }
    const int bqb = b0 + 4 * (lane & 15);
    double drv0[4], drv1[4], drvS;
    {
        #pragma unroll
        for (int j = 0; j < 4; ++j) {
            int bi = bqb + j; if (bi >= B) bi = B - 1;
            int a = actions[bi];
            int cs = ((a == 0) ? 5 : (a == 1) ? 1 : (a == 2) ? 3 : (a == 3) ? 7 : 4) * 16;
            double ic0 = (r0 >= cs && r0 < cs + 16) ? 5.0 : 0.0;
            double ic1 = (r1 >= cs && r1 < cs + 16) ? 5.0 : 0.0;
            drv0[j] = 0.5 * ic0 - 0.5 * inh0[j];
            drv1[j] = 0.5 * ic1 - 0.5 * inh1[j];
        }
        int bi = b0 + lane; if (bi >= B) bi = B - 1;
        int a = actions[bi];
        int cs = ((a == 0) ? 5 : (a == 1) ? 1 : (a == 2) ? 3 : (a == 3) ? 7 : 4) * 16;
        double icS = (srow >= cs && srow < cs + 16) ? 5.0 : 0.0;
        drvS = 0.5 * icS - 0.5 * inhS;
    }

    double vq0[4] = {0,0,0,0}, vq1[4] = {0,0,0,0}, vS = 0.0;
    float  aq0[4] = {0,0,0,0}, aq1[4] = {0,0,0,0}, aS = 0.0f;

    for (int tk = 0; tk < ticks; ++tk) {
        __syncthreads();   // prev tick's acc writes (or initial zeros) visible
        const unsigned rbOff = (tk & 1) ? 36864u : 0u;
        const unsigned lroQ  = (unsigned)((lane & 15) * 16) + rbOff;
        const unsigned lroS  = (unsigned)(lane * 4) + rbOff;
        char* WbB = (char*)ldsB + ((tk & 1) ? 0u : 36864u);

        QUAD_SEC(qO0, qk0, r0, drv0, vq0, aq0);
        QUAD_SEC(qO1, qk1, r1, drv1, vq1, aq1);

        {   // solo row: R7's b32 pipeline
            const uint4* ps = (const uint4*)(wsS + sO) + vz;
            uint4 A0 = ps[0], A1 = ps[1], B0q = ps[2], B1q = ps[3];
            double recS = 0.0;
            int k = 0;
            for (; k + 8 <= sk; k += 8) {
                GS4(A0, A1);   A0 = ps[4]; A1 = ps[5];
                GS4(B0q, B1q); B0q = ps[6]; B1q = ps[7];
                ps += 4;
            }
            if (k < sk) { GS4(A0, A1); }     // sk % 8 == 4 leftover
            double x = drvS + 0.3 * ((srow < NE) ? recS : -recS);
            double vv = vS;
            vv += (x - vv) * 0.5;
            double sd = (vv >= 1.0) ? 1.0 : 0.0;
            vv *= (1.0 - sd);
            vS = vv;
            aS += (float)sd;
            *(float*)(WbB + (unsigned)srow * 256u + lane * 4) = aS;
        }
    }

    // output: integer spike counts for excitatory neurons
    #pragma unroll
    for (int j = 0; j < 4; ++j) {
        int bi = bqb + j;
        if (bi < B) {
            if (r0 < NE) out[(size_t)bi * NE + r0] = aq0[j];
            if (r1 < NE) out[(size_t)bi * NE + r1] = aq1[j];
        }
    }
    if (b0 + lane < B && srow < NE) out[(size_t)(b0 + lane) * NE + srow] = aS;
}

extern "C" void kernel_launch(void* const* d_in, const int* in_sizes, int n_in,
                              void* d_out, int out_size, void* d_ws, size_t ws_size,
                              hipStream_t stream) {
    const int*   actions = (const int*)  d_in[0];
    const float* spk     = (const float*)d_in[1];
    const float* W_rec   = (const float*)d_in[2];
    const float* W_inh   = (const float*)d_in[3];
    const int*   nt      = (const int*)  d_in[4];
    float* out = (float*)d_out;
    int B = in_sizes[0];

    int*  meta = (int*)d_ws;
    char* wsB  = (char*)d_ws;

    prep_kernel<<<1, 256, 0, stream>>>(W_rec, meta, wsB);
    int nblocks = (B + NB - 1) / NB;
    snn_kernel<<<nblocks, THREADS, 0, stream>>>(actions, spk, W_inh, meta, wsB,
                                                nt, out, B);
}